// Round 4
// baseline (42.585 us; speedup 1.0000x reference)
//
#include <hip/hip_runtime.h>
#include <math.h>

#define BATCH 512
#define HW 12544                 // 112*112
#define PARTS 4                  // blocks per sample
#define VECS (HW / 4)            // 3136 float4 per plane
#define VEC_PER_PART (VECS / PARTS)  // 784 = 3*256 + 16
#define NBLK (BATCH * PARTS)     // 2048 blocks

#define INV512 (1.0f / 512.0f)
#define INVHW512 (1.0f / (512.0f * 12544.0f))
#define FIXED_SCALE 1099511627776.0   // 2^40

// Single fused kernel. Each block:
//  - streams its quarter of the 3 channel-1 planes (9 unrolled float4 loads/thread)
//  - lane 255 computes the per-sample scalar terms (hidden under streaming)
//  - tid 0 packs {1 arrival, fixed-point contribution} into ONE 64-bit atomicAdd.
//    Integer adds are associative -> deterministic total irrespective of order.
//  - the block that observes old>>52 == NBLK-1 unpacks the total and writes out.
// No fences, no cache flushes: the data travels through the coherence-point RMW.
__global__ __launch_bounds__(256) void combine_loss_fused(
        const float* __restrict__ preds1,
        const float* __restrict__ cams1,
        const float* __restrict__ preds1_back,
        const float* __restrict__ preds2,
        const float* __restrict__ cams2,
        const int* __restrict__ y,
        const int* __restrict__ d_index,
        unsigned long long* __restrict__ acc,   // zeroed per call
        float* __restrict__ out) {
    const int blk = blockIdx.x;
    const int b = blk >> 2;      // PARTS == 4
    const int p = blk & 3;
    const int tid = threadIdx.x;
    const int idx = d_index[0] & 1;

    __shared__ float r_er[4];
    __shared__ float r_sd[4];
    __shared__ float sA, sB, sC;

    // ---- per-sample scalar math on one lane (overlaps the streaming below) ----
    if (tid == 255) {
        const float p1a = preds1[(size_t)(idx * BATCH + b) * 2 + 0];
        const float p1b = preds1[(size_t)(idx * BATCH + b) * 2 + 1];
        const float poa = preds1[(size_t)((1 - idx) * BATCH + b) * 2 + 0];
        const float pob = preds1[(size_t)((1 - idx) * BATCH + b) * 2 + 1];
        const float p2a = preds2[(size_t)(idx * BATCH + b) * 2 + 0];
        const float p2b = preds2[(size_t)(idx * BATCH + b) * 2 + 1];
        const float pba = preds1_back[(size_t)(idx * BATCH + b) * 2 + 0];
        const float pbb = preds1_back[(size_t)(idx * BATCH + b) * 2 + 1];
        const int yi = y[b];
        const float yf = (float)yi;

        float m1 = fmaxf(p1a, p1b);
        float lse1 = m1 + logf(expf(p1a - m1) + expf(p1b - m1));
        float m2 = fmaxf(p2a, p2b);
        float lse2 = m2 + logf(expf(p2a - m2) + expf(p2b - m2));
        float mb = fmaxf(pba, pbb);
        float lseb = mb + logf(expf(pba - mb) + expf(pbb - mb));

        const float ce1 = lse1 - (yi == 1 ? p1b : p1a);
        const float ce2 = lse2 - (yi == 1 ? p2b : p2a);
        const float ce = 0.5f * (ce1 + ce2);
        const float ce_back = 0.5f * (lseb - pba) * yf;

        const float prob1 = expf(p1b - lse1);
        const int cur_pred = (p1b > p1a) ? 1 : 0;
        const int flag_pred = (pob > poa) ? 1 : 0;
        const bool cond = (cur_pred != flag_pred) && (cur_pred == 0) && (yi == 1);
        const float w = cond ? prob1 : 1.0f;
        const float same = (cur_pred == flag_pred) ? yf : 0.f;

        sA = w * (ce + ce_back) * INV512;
        sB = w * yf * INVHW512;
        sC = same * INVHW512;
    }

    // ---- stream the three planes: 9 unconditional loads + 16-thread tail ----
    const size_t cur_off = ((size_t)(idx * BATCH + b) * 2 + 1) * (size_t)HW;
    const size_t oth_off = ((size_t)((1 - idx) * BATCH + b) * 2 + 1) * (size_t)HW;
    const float4* __restrict__ c1 = (const float4*)(cams1 + cur_off);
    const float4* __restrict__ c2 = (const float4*)(cams2 + cur_off);
    const float4* __restrict__ tg = (const float4*)(cams1 + oth_off);

    const int i0 = p * VEC_PER_PART + tid;
    const int i1 = i0 + 256;
    const int i2 = i0 + 512;

    float4 a0 = c1[i0], b0 = c2[i0], t0 = tg[i0];
    float4 a1 = c1[i1], b1 = c2[i1], t1 = tg[i1];
    float4 a2 = c1[i2], b2 = c2[i2], t2 = tg[i2];

    float s_er = 0.f, s_sd = 0.f;
    {
        float d0 = a0.x - b0.x, d1 = a0.y - b0.y, d2 = a0.z - b0.z, d3 = a0.w - b0.w;
        s_er += d0 * d0 + d1 * d1 + d2 * d2 + d3 * d3;
        float e0 = a0.x - t0.x, e1 = a0.y - t0.y, e2 = a0.z - t0.z, e3 = a0.w - t0.w;
        s_sd += e0 * e0 + e1 * e1 + e2 * e2 + e3 * e3;
    }
    {
        float d0 = a1.x - b1.x, d1 = a1.y - b1.y, d2 = a1.z - b1.z, d3 = a1.w - b1.w;
        s_er += d0 * d0 + d1 * d1 + d2 * d2 + d3 * d3;
        float e0 = a1.x - t1.x, e1 = a1.y - t1.y, e2 = a1.z - t1.z, e3 = a1.w - t1.w;
        s_sd += e0 * e0 + e1 * e1 + e2 * e2 + e3 * e3;
    }
    {
        float d0 = a2.x - b2.x, d1 = a2.y - b2.y, d2 = a2.z - b2.z, d3 = a2.w - b2.w;
        s_er += d0 * d0 + d1 * d1 + d2 * d2 + d3 * d3;
        float e0 = a2.x - t2.x, e1 = a2.y - t2.y, e2 = a2.z - t2.z, e3 = a2.w - t2.w;
        s_sd += e0 * e0 + e1 * e1 + e2 * e2 + e3 * e3;
    }
    if (tid < 16) {  // indices 768..783 of this quarter
        const int i3 = p * VEC_PER_PART + 768 + tid;
        float4 a3 = c1[i3], b3 = c2[i3], t3 = tg[i3];
        float d0 = a3.x - b3.x, d1 = a3.y - b3.y, d2 = a3.z - b3.z, d3 = a3.w - b3.w;
        s_er += d0 * d0 + d1 * d1 + d2 * d2 + d3 * d3;
        float e0 = a3.x - t3.x, e1 = a3.y - t3.y, e2 = a3.z - t3.z, e3 = a3.w - t3.w;
        s_sd += e0 * e0 + e1 * e1 + e2 * e2 + e3 * e3;
    }

    // ---- block reduction ----
    for (int o = 32; o > 0; o >>= 1) {
        s_er += __shfl_down(s_er, o);
        s_sd += __shfl_down(s_sd, o);
    }
    const int wid = tid >> 6;
    const int lane = tid & 63;
    if (lane == 0) { r_er[wid] = s_er; r_sd[wid] = s_sd; }
    __syncthreads();

    if (tid == 0) {
        const float er_part = r_er[0] + r_er[1] + r_er[2] + r_er[3];
        const float sd_part = r_sd[0] + r_sd[1] + r_sd[2] + r_sd[3];
        float contrib = (p == 0 ? sA : 0.f) + sB * er_part + sC * sd_part;
        contrib = fmaxf(contrib, 0.f);  // mathematically >=0; guard fp wrap

        const unsigned long long pack =
            (unsigned long long)__double2ll_rn((double)contrib * FIXED_SCALE)
            | (1ULL << 52);
        const unsigned long long old = atomicAdd(acc, pack);
        if ((old >> 52) == (unsigned long long)(NBLK - 1)) {
            const unsigned long long total = (old + pack) & ((1ULL << 52) - 1ULL);
            out[0] = (float)((double)total * (1.0 / FIXED_SCALE));
        }
    }
}

extern "C" void kernel_launch(void* const* d_in, const int* in_sizes, int n_in,
                              void* d_out, int out_size, void* d_ws, size_t ws_size,
                              hipStream_t stream) {
    const float* preds1      = (const float*)d_in[0];
    const float* cams1       = (const float*)d_in[1];
    const float* preds1_back = (const float*)d_in[2];
    const float* preds2      = (const float*)d_in[3];
    const float* cams2       = (const float*)d_in[4];
    const int*   y           = (const int*)d_in[5];
    const int*   d_index     = (const int*)d_in[6];
    float* out = (float*)d_out;
    unsigned long long* acc = (unsigned long long*)d_ws;

    hipMemsetAsync(acc, 0, sizeof(unsigned long long), stream);
    combine_loss_fused<<<NBLK, 256, 0, stream>>>(
        preds1, cams1, preds1_back, preds2, cams2, y, d_index, acc, out);
}

// Round 5
// 25.188 us; speedup vs baseline: 1.6907x; 1.6907x over previous
//
#include <hip/hip_runtime.h>
#include <math.h>

#define BATCH 512
#define HW 12544                 // 112*112
#define PARTS 4                  // blocks per sample
#define VECS (HW / 4)            // 3136 float4 per plane
#define VEC_PER_PART (VECS / PARTS)  // 784 = 3*256 + 16
#define NBLK (BATCH * PARTS)     // 2048 blocks
#define GROUPS 64                // level-1 reduction lines
#define GROUP_STRIDE 32          // ULLs between lines (256 B, no false sharing)

#define INV512 (1.0f / 512.0f)
#define INVHW512 (1.0f / (512.0f * 12544.0f))
#define FIXED_SCALE 1099511627776.0   // 2^40
#define DATA_MASK ((1ULL << 52) - 1ULL)

// Single fused kernel with two-level packed-atomic reduction.
//  level 1: 2048 blocks -> 64 lines (32 same-line RMWs each, parallel across lines)
//  level 2: 64 group-last-arrivers -> 1 final line
//  final arriver unpacks and writes the scalar output.
// Packing: bits [0,52) fixed-point sum (scale 2^40), bits [52,..) arrival count.
// Integer adds are associative -> deterministic; data flows through the RMWs,
// so no fences / cache flushes are needed (R2's failure mode avoided).
__global__ __launch_bounds__(256) void combine_loss_fused(
        const float* __restrict__ preds1,
        const float* __restrict__ cams1,
        const float* __restrict__ preds1_back,
        const float* __restrict__ preds2,
        const float* __restrict__ cams2,
        const int* __restrict__ y,
        const int* __restrict__ d_index,
        unsigned long long* __restrict__ acc,   // GROUPS*GROUP_STRIDE+1 ULLs, zeroed per call
        float* __restrict__ out) {
    const int blk = blockIdx.x;
    const int b = blk >> 2;      // PARTS == 4
    const int p = blk & 3;
    const int tid = threadIdx.x;
    const int idx = d_index[0] & 1;

    __shared__ float r_er[4];
    __shared__ float r_sd[4];
    __shared__ float sA, sB, sC;

    // ---- issue all streaming loads FIRST (9 float4/thread + 16-thread tail) ----
    const size_t cur_off = ((size_t)(idx * BATCH + b) * 2 + 1) * (size_t)HW;
    const size_t oth_off = ((size_t)((1 - idx) * BATCH + b) * 2 + 1) * (size_t)HW;
    const float4* __restrict__ c1 = (const float4*)(cams1 + cur_off);
    const float4* __restrict__ c2 = (const float4*)(cams2 + cur_off);
    const float4* __restrict__ tg = (const float4*)(cams1 + oth_off);

    const int i0 = p * VEC_PER_PART + tid;
    const int i1 = i0 + 256;
    const int i2 = i0 + 512;

    float4 a0 = c1[i0], b0 = c2[i0], t0 = tg[i0];
    float4 a1 = c1[i1], b1 = c2[i1], t1 = tg[i1];
    float4 a2 = c1[i2], b2 = c2[i2], t2 = tg[i2];
    float4 a3, b3, t3;
    if (tid < 16) {  // indices 768..783 of this quarter
        const int i3 = p * VEC_PER_PART + 768 + tid;
        a3 = c1[i3]; b3 = c2[i3]; t3 = tg[i3];
    }

    // ---- per-sample scalar math on one lane (overlaps load returns) ----
    if (tid == 255) {
        const float p1a = preds1[(size_t)(idx * BATCH + b) * 2 + 0];
        const float p1b = preds1[(size_t)(idx * BATCH + b) * 2 + 1];
        const float poa = preds1[(size_t)((1 - idx) * BATCH + b) * 2 + 0];
        const float pob = preds1[(size_t)((1 - idx) * BATCH + b) * 2 + 1];
        const float p2a = preds2[(size_t)(idx * BATCH + b) * 2 + 0];
        const float p2b = preds2[(size_t)(idx * BATCH + b) * 2 + 1];
        const float pba = preds1_back[(size_t)(idx * BATCH + b) * 2 + 0];
        const float pbb = preds1_back[(size_t)(idx * BATCH + b) * 2 + 1];
        const int yi = y[b];
        const float yf = (float)yi;

        float m1 = fmaxf(p1a, p1b);
        float lse1 = m1 + logf(expf(p1a - m1) + expf(p1b - m1));
        float m2 = fmaxf(p2a, p2b);
        float lse2 = m2 + logf(expf(p2a - m2) + expf(p2b - m2));
        float mb = fmaxf(pba, pbb);
        float lseb = mb + logf(expf(pba - mb) + expf(pbb - mb));

        const float ce1 = lse1 - (yi == 1 ? p1b : p1a);
        const float ce2 = lse2 - (yi == 1 ? p2b : p2a);
        const float ce = 0.5f * (ce1 + ce2);
        const float ce_back = 0.5f * (lseb - pba) * yf;

        const float prob1 = expf(p1b - lse1);
        const int cur_pred = (p1b > p1a) ? 1 : 0;
        const int flag_pred = (pob > poa) ? 1 : 0;
        const bool cond = (cur_pred != flag_pred) && (cur_pred == 0) && (yi == 1);
        const float w = cond ? prob1 : 1.0f;
        const float same = (cur_pred == flag_pred) ? yf : 0.f;

        sA = w * (ce + ce_back) * INV512;
        sB = w * yf * INVHW512;
        sC = same * INVHW512;
    }

    // ---- consume loads ----
    float s_er = 0.f, s_sd = 0.f;
    {
        float d0 = a0.x - b0.x, d1 = a0.y - b0.y, d2 = a0.z - b0.z, d3 = a0.w - b0.w;
        s_er += d0 * d0 + d1 * d1 + d2 * d2 + d3 * d3;
        float e0 = a0.x - t0.x, e1 = a0.y - t0.y, e2 = a0.z - t0.z, e3 = a0.w - t0.w;
        s_sd += e0 * e0 + e1 * e1 + e2 * e2 + e3 * e3;
    }
    {
        float d0 = a1.x - b1.x, d1 = a1.y - b1.y, d2 = a1.z - b1.z, d3 = a1.w - b1.w;
        s_er += d0 * d0 + d1 * d1 + d2 * d2 + d3 * d3;
        float e0 = a1.x - t1.x, e1 = a1.y - t1.y, e2 = a1.z - t1.z, e3 = a1.w - t1.w;
        s_sd += e0 * e0 + e1 * e1 + e2 * e2 + e3 * e3;
    }
    {
        float d0 = a2.x - b2.x, d1 = a2.y - b2.y, d2 = a2.z - b2.z, d3 = a2.w - b2.w;
        s_er += d0 * d0 + d1 * d1 + d2 * d2 + d3 * d3;
        float e0 = a2.x - t2.x, e1 = a2.y - t2.y, e2 = a2.z - t2.z, e3 = a2.w - t2.w;
        s_sd += e0 * e0 + e1 * e1 + e2 * e2 + e3 * e3;
    }
    if (tid < 16) {
        float d0 = a3.x - b3.x, d1 = a3.y - b3.y, d2 = a3.z - b3.z, d3 = a3.w - b3.w;
        s_er += d0 * d0 + d1 * d1 + d2 * d2 + d3 * d3;
        float e0 = a3.x - t3.x, e1 = a3.y - t3.y, e2 = a3.z - t3.z, e3 = a3.w - t3.w;
        s_sd += e0 * e0 + e1 * e1 + e2 * e2 + e3 * e3;
    }

    // ---- block reduction ----
    for (int o = 32; o > 0; o >>= 1) {
        s_er += __shfl_down(s_er, o);
        s_sd += __shfl_down(s_sd, o);
    }
    const int wid = tid >> 6;
    const int lane = tid & 63;
    if (lane == 0) { r_er[wid] = s_er; r_sd[wid] = s_sd; }
    __syncthreads();

    if (tid == 0) {
        const float er_part = r_er[0] + r_er[1] + r_er[2] + r_er[3];
        const float sd_part = r_sd[0] + r_sd[1] + r_sd[2] + r_sd[3];
        float contrib = (p == 0 ? sA : 0.f) + sB * er_part + sC * sd_part;
        contrib = fmaxf(contrib, 0.f);  // mathematically >=0; guard fp wrap

        const unsigned long long pack =
            (unsigned long long)__double2ll_rn((double)contrib * FIXED_SCALE)
            | (1ULL << 52);
        const int g = blk >> 5;  // 64 groups of 32 blocks
        const unsigned long long old = atomicAdd(&acc[g * GROUP_STRIDE], pack);
        if ((old >> 52) == 31ULL) {  // last of my group
            const unsigned long long gtotal = (old + pack) & DATA_MASK;
            const unsigned long long pack2 = gtotal | (1ULL << 52);
            const unsigned long long old2 =
                atomicAdd(&acc[GROUPS * GROUP_STRIDE], pack2);
            if ((old2 >> 52) == (unsigned long long)(GROUPS - 1)) {
                const unsigned long long total = (old2 + pack2) & DATA_MASK;
                out[0] = (float)((double)total * (1.0 / FIXED_SCALE));
            }
        }
    }
}

extern "C" void kernel_launch(void* const* d_in, const int* in_sizes, int n_in,
                              void* d_out, int out_size, void* d_ws, size_t ws_size,
                              hipStream_t stream) {
    const float* preds1      = (const float*)d_in[0];
    const float* cams1       = (const float*)d_in[1];
    const float* preds1_back = (const float*)d_in[2];
    const float* preds2      = (const float*)d_in[3];
    const float* cams2       = (const float*)d_in[4];
    const int*   y           = (const int*)d_in[5];
    const int*   d_index     = (const int*)d_in[6];
    float* out = (float*)d_out;
    unsigned long long* acc = (unsigned long long*)d_ws;

    // zero level-1 lines + final line
    hipMemsetAsync(acc, 0, (GROUPS * GROUP_STRIDE + 1) * sizeof(unsigned long long),
                   stream);
    combine_loss_fused<<<NBLK, 256, 0, stream>>>(
        preds1, cams1, preds1_back, preds2, cams2, y, d_index, acc, out);
}

// Round 6
// 12.718 us; speedup vs baseline: 3.3485x; 1.9806x over previous
//
#include <hip/hip_runtime.h>
#include <math.h>

#define BATCH 512
#define HW 12544                 // 112*112
#define PARTS 4                  // blocks per sample
#define VECS (HW / 4)            // 3136 float4 per plane
#define VEC_PER_PART (VECS / PARTS)  // 784 = 3*256 + 16
#define NBLK (BATCH * PARTS)     // 2048 blocks

// ws layout (floats):
//   [0 .. NBLK*2)            per-block partials {er, sd}
//   [NBLK*2 .. NBLK*2+B*3)   per-sample scalars {A, B, C}
#define WS_SCALARS (NBLK * 2)

// Kernel 1: stream only the planes the loss actually needs.
//   er needs (c1,c2)  iff y==1
//   sd needs (tg)     iff y==1 && same==1
// Masks are block-uniform -> uniform branches, no divergence.
// y==0 blocks write zero partials and exit (~half the grid).
__global__ __launch_bounds__(256) void combine_loss_partials(
        const float* __restrict__ preds1,
        const float* __restrict__ cams1,
        const float* __restrict__ preds1_back,
        const float* __restrict__ preds2,
        const float* __restrict__ cams2,
        const int* __restrict__ y,
        const int* __restrict__ d_index,
        float* __restrict__ ws) {
    const int blk = blockIdx.x;
    const int b = blk >> 2;      // PARTS == 4
    const int p = blk & 3;
    const int tid = threadIdx.x;
    const int idx = d_index[0] & 1;

    // block-uniform scalars (broadcast loads)
    const int yi = y[b];
    const float p1a = preds1[(size_t)(idx * BATCH + b) * 2 + 0];
    const float p1b = preds1[(size_t)(idx * BATCH + b) * 2 + 1];
    const float poa = preds1[(size_t)((1 - idx) * BATCH + b) * 2 + 0];
    const float pob = preds1[(size_t)((1 - idx) * BATCH + b) * 2 + 1];
    const int cur_pred = (p1b > p1a) ? 1 : 0;   // argmax, tie -> 0 (matches jnp)
    const int flag_pred = (pob > poa) ? 1 : 0;
    const bool same_flag = (cur_pred == flag_pred);

    // per-sample scalar coefficients (one lane of p==0 blocks; all y)
    if (p == 0 && tid == 255) {
        const float p2a = preds2[(size_t)(idx * BATCH + b) * 2 + 0];
        const float p2b = preds2[(size_t)(idx * BATCH + b) * 2 + 1];
        const float pba = preds1_back[(size_t)(idx * BATCH + b) * 2 + 0];
        const float pbb = preds1_back[(size_t)(idx * BATCH + b) * 2 + 1];
        const float yf = (float)yi;

        float m1 = fmaxf(p1a, p1b);
        float lse1 = m1 + logf(expf(p1a - m1) + expf(p1b - m1));
        float m2 = fmaxf(p2a, p2b);
        float lse2 = m2 + logf(expf(p2a - m2) + expf(p2b - m2));
        float mb = fmaxf(pba, pbb);
        float lseb = mb + logf(expf(pba - mb) + expf(pbb - mb));

        const float ce1 = lse1 - (yi == 1 ? p1b : p1a);
        const float ce2 = lse2 - (yi == 1 ? p2b : p2a);
        const float ce = 0.5f * (ce1 + ce2);
        const float ce_back = 0.5f * (lseb - pba) * yf;

        const float prob1 = expf(p1b - lse1);
        const bool cond = (!same_flag) && (cur_pred == 0) && (yi == 1);
        const float w = cond ? prob1 : 1.0f;
        const float same = same_flag ? yf : 0.f;

        ws[WS_SCALARS + b * 3 + 0] = w * (ce + ce_back);     // A
        ws[WS_SCALARS + b * 3 + 1] = w * yf / (float)HW;     // B (er factor)
        ws[WS_SCALARS + b * 3 + 2] = same;                   // C (sd factor)
    }

    if (yi == 0) {
        // er and sd terms are exactly zero (B==C==0); keep partials finite.
        if (tid == 0) {
            ws[(size_t)blk * 2 + 0] = 0.f;
            ws[(size_t)blk * 2 + 1] = 0.f;
        }
        return;
    }

    // ---- stream the needed planes (uniform branches) ----
    const size_t cur_off = ((size_t)(idx * BATCH + b) * 2 + 1) * (size_t)HW;
    const size_t oth_off = ((size_t)((1 - idx) * BATCH + b) * 2 + 1) * (size_t)HW;
    const float4* __restrict__ c1 = (const float4*)(cams1 + cur_off);
    const float4* __restrict__ c2 = (const float4*)(cams2 + cur_off);
    const float4* __restrict__ tg = (const float4*)(cams1 + oth_off);

    const int i0 = p * VEC_PER_PART + tid;
    const int i1 = i0 + 256;
    const int i2 = i0 + 512;
    const int i3 = p * VEC_PER_PART + 768 + tid;  // valid when tid<16

    float4 a0 = c1[i0], b0 = c2[i0];
    float4 a1 = c1[i1], b1 = c2[i1];
    float4 a2 = c1[i2], b2 = c2[i2];
    float4 a3, b3;
    if (tid < 16) { a3 = c1[i3]; b3 = c2[i3]; }

    float4 t0, t1, t2, t3;
    if (same_flag) {
        t0 = tg[i0]; t1 = tg[i1]; t2 = tg[i2];
        if (tid < 16) { t3 = tg[i3]; }
    }

    float s_er = 0.f, s_sd = 0.f;
    {
        float d0 = a0.x - b0.x, d1 = a0.y - b0.y, d2 = a0.z - b0.z, d3 = a0.w - b0.w;
        s_er += d0 * d0 + d1 * d1 + d2 * d2 + d3 * d3;
        float e0 = a1.x - b1.x, e1 = a1.y - b1.y, e2 = a1.z - b1.z, e3 = a1.w - b1.w;
        s_er += e0 * e0 + e1 * e1 + e2 * e2 + e3 * e3;
        float f0 = a2.x - b2.x, f1 = a2.y - b2.y, f2 = a2.z - b2.z, f3 = a2.w - b2.w;
        s_er += f0 * f0 + f1 * f1 + f2 * f2 + f3 * f3;
    }
    if (tid < 16) {
        float d0 = a3.x - b3.x, d1 = a3.y - b3.y, d2 = a3.z - b3.z, d3 = a3.w - b3.w;
        s_er += d0 * d0 + d1 * d1 + d2 * d2 + d3 * d3;
    }
    if (same_flag) {
        float d0 = a0.x - t0.x, d1 = a0.y - t0.y, d2 = a0.z - t0.z, d3 = a0.w - t0.w;
        s_sd += d0 * d0 + d1 * d1 + d2 * d2 + d3 * d3;
        float e0 = a1.x - t1.x, e1 = a1.y - t1.y, e2 = a1.z - t1.z, e3 = a1.w - t1.w;
        s_sd += e0 * e0 + e1 * e1 + e2 * e2 + e3 * e3;
        float f0 = a2.x - t2.x, f1 = a2.y - t2.y, f2 = a2.z - t2.z, f3 = a2.w - t2.w;
        s_sd += f0 * f0 + f1 * f1 + f2 * f2 + f3 * f3;
        if (tid < 16) {
            float d0 = a3.x - t3.x, d1 = a3.y - t3.y, d2 = a3.z - t3.z, d3 = a3.w - t3.w;
            s_sd += d0 * d0 + d1 * d1 + d2 * d2 + d3 * d3;
        }
    }

    // ---- block reduction ----
    for (int o = 32; o > 0; o >>= 1) {
        s_er += __shfl_down(s_er, o);
        s_sd += __shfl_down(s_sd, o);
    }
    __shared__ float r_er[4];
    __shared__ float r_sd[4];
    const int wid = tid >> 6;
    const int lane = tid & 63;
    if (lane == 0) { r_er[wid] = s_er; r_sd[wid] = s_sd; }
    __syncthreads();
    if (tid == 0) {
        ws[(size_t)blk * 2 + 0] = r_er[0] + r_er[1] + r_er[2] + r_er[3];
        ws[(size_t)blk * 2 + 1] = same_flag ? (r_sd[0] + r_sd[1] + r_sd[2] + r_sd[3])
                                            : 0.f;
    }
}

// Kernel 2: pure gather + FMA + reduce. One block, 512 threads.
__global__ __launch_bounds__(512) void combine_loss_finalize(
        const float* __restrict__ ws,
        float* __restrict__ out) {
    const int b = threadIdx.x;  // sample id

    float er_sum = 0.f, sd_sum = 0.f;
    #pragma unroll
    for (int q = 0; q < PARTS; ++q) {
        er_sum += ws[(size_t)(b * PARTS + q) * 2 + 0];
        sd_sum += ws[(size_t)(b * PARTS + q) * 2 + 1];
    }
    const float A = ws[WS_SCALARS + b * 3 + 0];
    const float B = ws[WS_SCALARS + b * 3 + 1];
    const float C = ws[WS_SCALARS + b * 3 + 2];

    float loss_b = A + B * er_sum;
    float sd_b = C * sd_sum;

    for (int o = 32; o > 0; o >>= 1) {
        loss_b += __shfl_down(loss_b, o);
        sd_b += __shfl_down(sd_b, o);
    }
    __shared__ float r_l[8];
    __shared__ float r_s[8];
    const int wid = b >> 6;
    const int lane = b & 63;
    if (lane == 0) { r_l[wid] = loss_b; r_s[wid] = sd_b; }
    __syncthreads();
    if (b == 0) {
        float ls = 0.f, ss = 0.f;
        #pragma unroll
        for (int wv = 0; wv < 8; ++wv) { ls += r_l[wv]; ss += r_s[wv]; }
        out[0] = ls / (float)BATCH + ss / ((float)BATCH * (float)HW);
    }
}

extern "C" void kernel_launch(void* const* d_in, const int* in_sizes, int n_in,
                              void* d_out, int out_size, void* d_ws, size_t ws_size,
                              hipStream_t stream) {
    const float* preds1      = (const float*)d_in[0];
    const float* cams1       = (const float*)d_in[1];
    const float* preds1_back = (const float*)d_in[2];
    const float* preds2      = (const float*)d_in[3];
    const float* cams2       = (const float*)d_in[4];
    const int*   y           = (const int*)d_in[5];
    const int*   d_index     = (const int*)d_in[6];
    float* out = (float*)d_out;
    float* ws = (float*)d_ws;

    combine_loss_partials<<<NBLK, 256, 0, stream>>>(
        preds1, cams1, preds1_back, preds2, cams2, y, d_index, ws);
    combine_loss_finalize<<<1, 512, 0, stream>>>(ws, out);
}

// Round 7
// 11.690 us; speedup vs baseline: 3.6427x; 1.0879x over previous
//
#include <hip/hip_runtime.h>
#include <math.h>

#define BATCH 512
#define HW 12544                 // 112*112
#define PARTS 4                  // blocks per sample
#define VECS (HW / 4)            // 3136 float4 per plane
#define VEC_PER_PART (VECS / PARTS)  // 784 = 3*256 + 16
#define NBLK (BATCH * PARTS)     // 2048 blocks

#define INV512 (1.0f / 512.0f)
#define INVHW512 (1.0f / (512.0f * 12544.0f))

// Kernel 1: each block streams only the planes its sample needs and writes a
// single pre-scaled float contribution ws[blk]:
//   contrib = (p==0 ? A' : 0) + B'*er_part + C'*sd_part
//   A' = w*(ce+ce_back)/512, B' = w*y/(512*HW), C' = same*y/(512*HW)
// Plane traffic: (c1,c2) iff y==1; tg additionally iff same==1. Masks are
// block-uniform -> uniform branches. Every ws[blk] written on every path.
__global__ __launch_bounds__(256) void combine_loss_partials(
        const float* __restrict__ preds1,
        const float* __restrict__ cams1,
        const float* __restrict__ preds1_back,
        const float* __restrict__ preds2,
        const float* __restrict__ cams2,
        const int* __restrict__ y,
        const int* __restrict__ d_index,
        float* __restrict__ ws) {
    const int blk = blockIdx.x;
    const int b = blk >> 2;      // PARTS == 4
    const int p = blk & 3;
    const int tid = threadIdx.x;
    const int idx = d_index[0] & 1;

    // block-uniform scalars (broadcast loads)
    const int yi = y[b];
    const float p1a = preds1[(size_t)(idx * BATCH + b) * 2 + 0];
    const float p1b = preds1[(size_t)(idx * BATCH + b) * 2 + 1];
    const float poa = preds1[(size_t)((1 - idx) * BATCH + b) * 2 + 0];
    const float pob = preds1[(size_t)((1 - idx) * BATCH + b) * 2 + 1];
    const int cur_pred = (p1b > p1a) ? 1 : 0;   // argmax, tie -> 0 (matches jnp)
    const int flag_pred = (pob > poa) ? 1 : 0;
    const bool same_flag = (cur_pred == flag_pred);
    const float yf = (float)yi;

    __shared__ float sA, sB, sC;

    if (yi == 0) {
        // er/sd vanish (B'=C'=0). Only p==0 carries A' = ce/512 (w=1, ce_back=0).
        if (tid == 255) {
            float A = 0.f;
            if (p == 0) {
                const float p2a = preds2[(size_t)(idx * BATCH + b) * 2 + 0];
                const float p2b = preds2[(size_t)(idx * BATCH + b) * 2 + 1];
                float m1 = fmaxf(p1a, p1b);
                float lse1 = m1 + logf(expf(p1a - m1) + expf(p1b - m1));
                float m2 = fmaxf(p2a, p2b);
                float lse2 = m2 + logf(expf(p2a - m2) + expf(p2b - m2));
                const float ce1 = lse1 - p1a;   // yi==0 -> class 0
                const float ce2 = lse2 - p2a;
                A = 0.5f * (ce1 + ce2) * INV512;
            }
            ws[blk] = A;
        }
        return;
    }

    // ---- y==1: issue streaming loads first ----
    const size_t cur_off = ((size_t)(idx * BATCH + b) * 2 + 1) * (size_t)HW;
    const size_t oth_off = ((size_t)((1 - idx) * BATCH + b) * 2 + 1) * (size_t)HW;
    const float4* __restrict__ c1 = (const float4*)(cams1 + cur_off);
    const float4* __restrict__ c2 = (const float4*)(cams2 + cur_off);
    const float4* __restrict__ tg = (const float4*)(cams1 + oth_off);

    const int i0 = p * VEC_PER_PART + tid;
    const int i1 = i0 + 256;
    const int i2 = i0 + 512;
    const int i3 = p * VEC_PER_PART + 768 + tid;  // valid when tid<16

    float4 a0 = c1[i0], b0 = c2[i0];
    float4 a1 = c1[i1], b1 = c2[i1];
    float4 a2 = c1[i2], b2 = c2[i2];
    float4 a3, b3;
    if (tid < 16) { a3 = c1[i3]; b3 = c2[i3]; }
    float4 t0, t1, t2, t3;
    if (same_flag) {
        t0 = tg[i0]; t1 = tg[i1]; t2 = tg[i2];
        if (tid < 16) { t3 = tg[i3]; }
    }

    // ---- coefficient math on one lane (hides under load returns) ----
    if (tid == 255) {
        float m1 = fmaxf(p1a, p1b);
        float lse1 = m1 + logf(expf(p1a - m1) + expf(p1b - m1));
        const bool cond = (!same_flag) && (cur_pred == 0);  // yi==1 here
        const float w = cond ? expf(p1b - lse1) : 1.0f;

        float A = 0.f;
        if (p == 0) {
            const float p2a = preds2[(size_t)(idx * BATCH + b) * 2 + 0];
            const float p2b = preds2[(size_t)(idx * BATCH + b) * 2 + 1];
            const float pba = preds1_back[(size_t)(idx * BATCH + b) * 2 + 0];
            const float pbb = preds1_back[(size_t)(idx * BATCH + b) * 2 + 1];
            float m2 = fmaxf(p2a, p2b);
            float lse2 = m2 + logf(expf(p2a - m2) + expf(p2b - m2));
            float mb = fmaxf(pba, pbb);
            float lseb = mb + logf(expf(pba - mb) + expf(pbb - mb));
            const float ce1 = lse1 - p1b;   // yi==1 -> class 1
            const float ce2 = lse2 - p2b;
            const float ce = 0.5f * (ce1 + ce2);
            const float ce_back = 0.5f * (lseb - pba);  // * yf(=1)
            A = w * (ce + ce_back) * INV512;
        }
        sA = A;
        sB = w * yf * INVHW512;
        sC = same_flag ? yf * INVHW512 : 0.f;
    }

    // ---- consume loads ----
    float s_er = 0.f, s_sd = 0.f;
    {
        float d0 = a0.x - b0.x, d1 = a0.y - b0.y, d2 = a0.z - b0.z, d3 = a0.w - b0.w;
        s_er += d0 * d0 + d1 * d1 + d2 * d2 + d3 * d3;
        float e0 = a1.x - b1.x, e1 = a1.y - b1.y, e2 = a1.z - b1.z, e3 = a1.w - b1.w;
        s_er += e0 * e0 + e1 * e1 + e2 * e2 + e3 * e3;
        float f0 = a2.x - b2.x, f1 = a2.y - b2.y, f2 = a2.z - b2.z, f3 = a2.w - b2.w;
        s_er += f0 * f0 + f1 * f1 + f2 * f2 + f3 * f3;
    }
    if (tid < 16) {
        float d0 = a3.x - b3.x, d1 = a3.y - b3.y, d2 = a3.z - b3.z, d3 = a3.w - b3.w;
        s_er += d0 * d0 + d1 * d1 + d2 * d2 + d3 * d3;
    }
    if (same_flag) {
        float d0 = a0.x - t0.x, d1 = a0.y - t0.y, d2 = a0.z - t0.z, d3 = a0.w - t0.w;
        s_sd += d0 * d0 + d1 * d1 + d2 * d2 + d3 * d3;
        float e0 = a1.x - t1.x, e1 = a1.y - t1.y, e2 = a1.z - t1.z, e3 = a1.w - t1.w;
        s_sd += e0 * e0 + e1 * e1 + e2 * e2 + e3 * e3;
        float f0 = a2.x - t2.x, f1 = a2.y - t2.y, f2 = a2.z - t2.z, f3 = a2.w - t2.w;
        s_sd += f0 * f0 + f1 * f1 + f2 * f2 + f3 * f3;
        if (tid < 16) {
            float d0 = a3.x - t3.x, d1 = a3.y - t3.y, d2 = a3.z - t3.z, d3 = a3.w - t3.w;
            s_sd += d0 * d0 + d1 * d1 + d2 * d2 + d3 * d3;
        }
    }

    // ---- block reduction ----
    for (int o = 32; o > 0; o >>= 1) {
        s_er += __shfl_down(s_er, o);
        s_sd += __shfl_down(s_sd, o);
    }
    __shared__ float r_er[4];
    __shared__ float r_sd[4];
    const int wid = tid >> 6;
    const int lane = tid & 63;
    if (lane == 0) { r_er[wid] = s_er; r_sd[wid] = s_sd; }
    __syncthreads();
    if (tid == 0) {
        const float er_part = r_er[0] + r_er[1] + r_er[2] + r_er[3];
        const float sd_part = r_sd[0] + r_sd[1] + r_sd[2] + r_sd[3];
        ws[blk] = sA + sB * er_part + sC * sd_part;
    }
}

// Kernel 2: fixed-order sum of NBLK pre-scaled floats. One block, 256 threads.
__global__ __launch_bounds__(256) void combine_loss_finalize(
        const float* __restrict__ ws,
        float* __restrict__ out) {
    const int t = threadIdx.x;
    const float4* __restrict__ v = (const float4*)ws;  // 512 float4
    float4 x0 = v[t];
    float4 x1 = v[t + 256];
    float s = ((x0.x + x0.y) + (x0.z + x0.w)) + ((x1.x + x1.y) + (x1.z + x1.w));

    for (int o = 32; o > 0; o >>= 1) s += __shfl_down(s, o);
    __shared__ float r[4];
    const int wid = t >> 6;
    const int lane = t & 63;
    if (lane == 0) r[wid] = s;
    __syncthreads();
    if (t == 0) out[0] = (r[0] + r[1]) + (r[2] + r[3]);
}

extern "C" void kernel_launch(void* const* d_in, const int* in_sizes, int n_in,
                              void* d_out, int out_size, void* d_ws, size_t ws_size,
                              hipStream_t stream) {
    const float* preds1      = (const float*)d_in[0];
    const float* cams1       = (const float*)d_in[1];
    const float* preds1_back = (const float*)d_in[2];
    const float* preds2      = (const float*)d_in[3];
    const float* cams2       = (const float*)d_in[4];
    const int*   y           = (const int*)d_in[5];
    const int*   d_index     = (const int*)d_in[6];
    float* out = (float*)d_out;
    float* ws = (float*)d_ws;

    combine_loss_partials<<<NBLK, 256, 0, stream>>>(
        preds1, cams1, preds1_back, preds2, cams2, y, d_index, ws);
    combine_loss_finalize<<<1, 256, 0, stream>>>(ws, out);
}

// Round 8
// 11.562 us; speedup vs baseline: 3.6831x; 1.0111x over previous
//
#include <hip/hip_runtime.h>
#include <math.h>

#define BATCH 512
#define HW 12544                 // 112*112
#define PARTS 4                  // blocks per sample
#define VECS (HW / 4)            // 3136 float4 per plane
#define VEC_PER_PART (VECS / PARTS)  // 784 = 3*256 + 16
#define NBLK (BATCH * PARTS)     // 2048 blocks

#define INV512 (1.0f / 512.0f)
#define INVHW512 (1.0f / (512.0f * 12544.0f))

// Kernel 1: each block streams only the planes its sample needs and writes a
// single pre-scaled float contribution ws[blk]:
//   contrib = (p==0 ? A' : 0) + B'*er_part + C'*sd_part
//   A' = w*(ce+ce_back)/512, B' = w*y/(512*HW), C' = same*y/(512*HW)
// Plane traffic: (c1,c2) iff y==1; tg additionally iff same==1. Masks are
// block-uniform -> uniform branches. Every ws[blk] written on every path.
__global__ __launch_bounds__(256) void combine_loss_partials(
        const float* __restrict__ preds1,
        const float* __restrict__ cams1,
        const float* __restrict__ preds1_back,
        const float* __restrict__ preds2,
        const float* __restrict__ cams2,
        const int* __restrict__ y,
        const int* __restrict__ d_index,
        float* __restrict__ ws) {
    const int blk = blockIdx.x;
    const int b = blk >> 2;      // PARTS == 4
    const int p = blk & 3;
    const int tid = threadIdx.x;
    const int idx = d_index[0] & 1;

    // block-uniform scalars (broadcast loads)
    const int yi = y[b];
    const float p1a = preds1[(size_t)(idx * BATCH + b) * 2 + 0];
    const float p1b = preds1[(size_t)(idx * BATCH + b) * 2 + 1];
    const float poa = preds1[(size_t)((1 - idx) * BATCH + b) * 2 + 0];
    const float pob = preds1[(size_t)((1 - idx) * BATCH + b) * 2 + 1];
    const int cur_pred = (p1b > p1a) ? 1 : 0;   // argmax, tie -> 0 (matches jnp)
    const int flag_pred = (pob > poa) ? 1 : 0;
    const bool same_flag = (cur_pred == flag_pred);
    const float yf = (float)yi;

    __shared__ float sA, sB, sC;

    if (yi == 0) {
        // er/sd vanish (B'=C'=0). Only p==0 carries A' = ce/512 (w=1, ce_back=0).
        if (tid == 255) {
            float A = 0.f;
            if (p == 0) {
                const float p2a = preds2[(size_t)(idx * BATCH + b) * 2 + 0];
                const float p2b = preds2[(size_t)(idx * BATCH + b) * 2 + 1];
                float m1 = fmaxf(p1a, p1b);
                float lse1 = m1 + logf(expf(p1a - m1) + expf(p1b - m1));
                float m2 = fmaxf(p2a, p2b);
                float lse2 = m2 + logf(expf(p2a - m2) + expf(p2b - m2));
                const float ce1 = lse1 - p1a;   // yi==0 -> class 0
                const float ce2 = lse2 - p2a;
                A = 0.5f * (ce1 + ce2) * INV512;
            }
            ws[blk] = A;
        }
        return;
    }

    // ---- y==1: issue streaming loads first ----
    const size_t cur_off = ((size_t)(idx * BATCH + b) * 2 + 1) * (size_t)HW;
    const size_t oth_off = ((size_t)((1 - idx) * BATCH + b) * 2 + 1) * (size_t)HW;
    const float4* __restrict__ c1 = (const float4*)(cams1 + cur_off);
    const float4* __restrict__ c2 = (const float4*)(cams2 + cur_off);
    const float4* __restrict__ tg = (const float4*)(cams1 + oth_off);

    const int i0 = p * VEC_PER_PART + tid;
    const int i1 = i0 + 256;
    const int i2 = i0 + 512;
    const int i3 = p * VEC_PER_PART + 768 + tid;  // valid when tid<16

    float4 a0 = c1[i0], b0 = c2[i0];
    float4 a1 = c1[i1], b1 = c2[i1];
    float4 a2 = c1[i2], b2 = c2[i2];
    float4 a3, b3;
    if (tid < 16) { a3 = c1[i3]; b3 = c2[i3]; }
    float4 t0, t1, t2, t3;
    if (same_flag) {
        t0 = tg[i0]; t1 = tg[i1]; t2 = tg[i2];
        if (tid < 16) { t3 = tg[i3]; }
    }

    // ---- coefficient math on one lane (hides under load returns) ----
    if (tid == 255) {
        float m1 = fmaxf(p1a, p1b);
        float lse1 = m1 + logf(expf(p1a - m1) + expf(p1b - m1));
        const bool cond = (!same_flag) && (cur_pred == 0);  // yi==1 here
        const float w = cond ? expf(p1b - lse1) : 1.0f;

        float A = 0.f;
        if (p == 0) {
            const float p2a = preds2[(size_t)(idx * BATCH + b) * 2 + 0];
            const float p2b = preds2[(size_t)(idx * BATCH + b) * 2 + 1];
            const float pba = preds1_back[(size_t)(idx * BATCH + b) * 2 + 0];
            const float pbb = preds1_back[(size_t)(idx * BATCH + b) * 2 + 1];
            float m2 = fmaxf(p2a, p2b);
            float lse2 = m2 + logf(expf(p2a - m2) + expf(p2b - m2));
            float mb = fmaxf(pba, pbb);
            float lseb = mb + logf(expf(pba - mb) + expf(pbb - mb));
            const float ce1 = lse1 - p1b;   // yi==1 -> class 1
            const float ce2 = lse2 - p2b;
            const float ce = 0.5f * (ce1 + ce2);
            const float ce_back = 0.5f * (lseb - pba);  // * yf(=1)
            A = w * (ce + ce_back) * INV512;
        }
        sA = A;
        sB = w * yf * INVHW512;
        sC = same_flag ? yf * INVHW512 : 0.f;
    }

    // ---- consume loads ----
    float s_er = 0.f, s_sd = 0.f;
    {
        float d0 = a0.x - b0.x, d1 = a0.y - b0.y, d2 = a0.z - b0.z, d3 = a0.w - b0.w;
        s_er += d0 * d0 + d1 * d1 + d2 * d2 + d3 * d3;
        float e0 = a1.x - b1.x, e1 = a1.y - b1.y, e2 = a1.z - b1.z, e3 = a1.w - b1.w;
        s_er += e0 * e0 + e1 * e1 + e2 * e2 + e3 * e3;
        float f0 = a2.x - b2.x, f1 = a2.y - b2.y, f2 = a2.z - b2.z, f3 = a2.w - b2.w;
        s_er += f0 * f0 + f1 * f1 + f2 * f2 + f3 * f3;
    }
    if (tid < 16) {
        float d0 = a3.x - b3.x, d1 = a3.y - b3.y, d2 = a3.z - b3.z, d3 = a3.w - b3.w;
        s_er += d0 * d0 + d1 * d1 + d2 * d2 + d3 * d3;
    }
    if (same_flag) {
        float d0 = a0.x - t0.x, d1 = a0.y - t0.y, d2 = a0.z - t0.z, d3 = a0.w - t0.w;
        s_sd += d0 * d0 + d1 * d1 + d2 * d2 + d3 * d3;
        float e0 = a1.x - t1.x, e1 = a1.y - t1.y, e2 = a1.z - t1.z, e3 = a1.w - t1.w;
        s_sd += e0 * e0 + e1 * e1 + e2 * e2 + e3 * e3;
        float f0 = a2.x - t2.x, f1 = a2.y - t2.y, f2 = a2.z - t2.z, f3 = a2.w - t2.w;
        s_sd += f0 * f0 + f1 * f1 + f2 * f2 + f3 * f3;
        if (tid < 16) {
            float d0 = a3.x - t3.x, d1 = a3.y - t3.y, d2 = a3.z - t3.z, d3 = a3.w - t3.w;
            s_sd += d0 * d0 + d1 * d1 + d2 * d2 + d3 * d3;
        }
    }

    // ---- block reduction (skip dead sd-tree when uniformly zero) ----
    for (int o = 32; o > 0; o >>= 1) s_er += __shfl_down(s_er, o);
    if (same_flag) {
        for (int o = 32; o > 0; o >>= 1) s_sd += __shfl_down(s_sd, o);
    }
    __shared__ float r_er[4];
    __shared__ float r_sd[4];
    const int wid = tid >> 6;
    const int lane = tid & 63;
    if (lane == 0) { r_er[wid] = s_er; r_sd[wid] = s_sd; }
    __syncthreads();
    if (tid == 0) {
        const float er_part = r_er[0] + r_er[1] + r_er[2] + r_er[3];
        const float sd_part = same_flag ? (r_sd[0] + r_sd[1] + r_sd[2] + r_sd[3]) : 0.f;
        ws[blk] = sA + sB * er_part + sC * sd_part;
    }
}

// Kernel 2: fixed-order sum of NBLK pre-scaled floats. ONE WAVE (64 threads):
// 8 float4/lane issued back-to-back, pure shuffle tree, no LDS, no barrier.
__global__ __launch_bounds__(64) void combine_loss_finalize(
        const float* __restrict__ ws,
        float* __restrict__ out) {
    const int t = threadIdx.x;  // 0..63
    const float4* __restrict__ v = (const float4*)ws;  // 512 float4

    float4 x0 = v[t];
    float4 x1 = v[t + 64];
    float4 x2 = v[t + 128];
    float4 x3 = v[t + 192];
    float4 x4 = v[t + 256];
    float4 x5 = v[t + 320];
    float4 x6 = v[t + 384];
    float4 x7 = v[t + 448];

    float s = ((x0.x + x0.y) + (x0.z + x0.w)) + ((x1.x + x1.y) + (x1.z + x1.w))
            + ((x2.x + x2.y) + (x2.z + x2.w)) + ((x3.x + x3.y) + (x3.z + x3.w))
            + ((x4.x + x4.y) + (x4.z + x4.w)) + ((x5.x + x5.y) + (x5.z + x5.w))
            + ((x6.x + x6.y) + (x6.z + x6.w)) + ((x7.x + x7.y) + (x7.z + x7.w));

    for (int o = 32; o > 0; o >>= 1) s += __shfl_down(s, o);
    if (t == 0) out[0] = s;
}

extern "C" void kernel_launch(void* const* d_in, const int* in_sizes, int n_in,
                              void* d_out, int out_size, void* d_ws, size_t ws_size,
                              hipStream_t stream) {
    const float* preds1      = (const float*)d_in[0];
    const float* cams1       = (const float*)d_in[1];
    const float* preds1_back = (const float*)d_in[2];
    const float* preds2      = (const float*)d_in[3];
    const float* cams2       = (const float*)d_in[4];
    const int*   y           = (const int*)d_in[5];
    const int*   d_index     = (const int*)d_in[6];
    float* out = (float*)d_out;
    float* ws = (float*)d_ws;

    combine_loss_partials<<<NBLK, 256, 0, stream>>>(
        preds1, cams1, preds1_back, preds2, cams2, y, d_index, ws);
    combine_loss_finalize<<<1, 64, 0, stream>>>(ws, out);
}